// Round 16
// baseline (108.916 us; speedup 1.0000x reference)
//
#include <hip/hip_runtime.h>

// images=8, patches=3600(=60*60), hor_f=64, ver_f=25(=5*5), 64x64 px, k=5
// ROUND 16 = ATTRIBUTION PROBE: identical to r15 except fold is launched TWICE
// (idempotent rewrite of the same slab) to measure steady-state fold duration
// as dur_us - 76.2.
#define OH     60
#define NIMG   8
#define HF     64
#define VF     25
#define NPATCH 3600
#define CDIM   1600                  // HF*VF

typedef float floatx4 __attribute__((ext_vector_type(4)));  // native vec for nt-store

// ---- fold (r15, unchanged): 1D grid 768, XCD-pinned: im = b & 7 ----
#define FH   8                       // h channels per block
#define FC   (FH * VF)               // 200 c values
#define SPI  5                       // pi rows per strip
#define PJS  64                      // pj stride (XOR-swizzled)
#define NSTRIP 12
#define SROWS  9                     // SPI + 4 halo rows

__global__ __launch_bounds__(512, 6) void fold_kernel(const float* __restrict__ x,
                                                      float* __restrict__ slab) {
    __shared__ float lb[FC * PJS];   // 51.2 KB
    const int b = blockIdx.x;
    const int im = b & 7;            // XCD pin (blockIdx round-robins mod 8)
    const int rem = b >> 3;          // 0..95
    const int hg = rem & 7, strip = rem >> 3;
    const int t = threadIdx.x;
    const int h0 = hg * FH;
    const int pi0 = strip * SPI;
    const int j = t & 63, g = t >> 6;          // g = local h (0..7)

    float acc[SROWS];
#pragma unroll
    for (int k = 0; k < SROWS; ++k) acc[k] = 0.f;

    const float* xb = x + ((size_t)im * NPATCH + (size_t)pi0 * OH) * CDIM + h0 * VF;

    int off_g[6], off_l[6];
#pragma unroll
    for (int k = 0; k < 6; ++k) {
        int u = t + 512 * k;
        if (u < 3000) {
            int pj = u / 50, c4 = u - 50 * pj;
            off_g[k] = pj * CDIM + (c4 << 2);
            off_l[k] = (c4 << 8) + (pj ^ (c4 & 31));
        }
    }

    float4 stg[6];
#pragma unroll
    for (int k = 0; k < 6; ++k)
        if (t + 512 * k < 3000)
            stg[k] = *reinterpret_cast<const float4*>(xb + off_g[k]);

#pragma unroll
    for (int row = 0; row < SPI; ++row) {
        if (row) __syncthreads();
#pragma unroll
        for (int k = 0; k < 6; ++k)
            if (t + 512 * k < 3000) {
                float4 v = stg[k];
                int a = off_l[k];
                lb[a]           = v.x;
                lb[a + PJS]     = v.y;
                lb[a + 2 * PJS] = v.z;
                lb[a + 3 * PJS] = v.w;
            }
        if (row + 1 < SPI) {                   // prefetch next row during compute
#pragma unroll
            for (int k = 0; k < 6; ++k)
                if (t + 512 * k < 3000)
                    stg[k] = *reinterpret_cast<const float4*>(
                        xb + (size_t)(row + 1) * OH * CDIM + off_g[k]);
        }
        __syncthreads();
#pragma unroll
        for (int di = 0; di < 5; ++di) {
#pragma unroll
            for (int dj = 0; dj < 5; ++dj) {
                int c = g * VF + di * 5 + dj;
                int pjr = j - dj;
                if ((unsigned)pjr < 60u)
                    acc[row + di] += lb[c * PJS + (pjr ^ ((c >> 2) & 31))];
            }
        }
    }

    float* sb = slab + (((size_t)(strip * 8 + im) * 64 + h0 + g) * SROWS) * 64 + j;
#pragma unroll
    for (int il = 0; il < SROWS; ++il) sb[il * 64] = acc[il];
}

// ---- unfold (r15, unchanged): 1D grid 1920, XCD-pinned, NT stores ----
#define UH   16                      // channels per block
#define LJS  68                      // padded j stride (f4-aligned)

__global__ __launch_bounds__(256) void unfold_kernel(const float* __restrict__ slab,
                                                     float* __restrict__ out) {
    __shared__ float li[UH * 5 * LJS];         // 5440 fl = 21.76 KB
    __shared__ int4 lut[100];
    const int b = blockIdx.x;
    const int im = b & 7;            // XCD pin
    const int rem = b >> 3;          // 0..239
    const int hh = rem & 3, pi = rem >> 2;     // hh 0..3, pi 0..59
    const int t = threadIdx.x;
    const int h0 = hh * UH;

    if (t < 100) {                             // f4-slot r -> 4 LDS offsets (R*LJS+dj)
        int4 e;
        int* ep = &e.x;
#pragma unroll
        for (int k = 0; k < 4; ++k) {
            int fl = 4 * t + k;                // = ho*25 + v
            int ho = fl / 25, v = fl - 25 * ho;
            int di = v / 5, dj = v - 5 * di;
            ep[k] = (ho * 5 + di) * LJS + dj;
        }
        lut[t] = e;
    }

    // stage rows pi..pi+4 of 16 channels (strip-summed), pre-scaled by 1/(ci*cj)
    for (int u = t; u < UH * 5 * 16; u += 256) {
        int ch = u / 80, rem2 = u - 80 * ch;
        int di = rem2 >> 4, j4 = rem2 & 15;
        int i = pi + di;
        int s_hi = min(i / 5, NSTRIP - 1);
        int s_lo = (i <= 8) ? 0 : (i - 4) / 5;
        const float* pa = slab +
            (((size_t)(s_lo * 8 + im) * 64 + h0 + ch) * SROWS + (i - 5 * s_lo)) * 64 + (j4 << 2);
        float4 v = *reinterpret_cast<const float4*>(pa);
        if (s_hi != s_lo) {
            const float* pb = slab +
                (((size_t)(s_hi * 8 + im) * 64 + h0 + ch) * SROWS + (i - 5 * s_hi)) * 64 + (j4 << 2);
            float4 w = *reinterpret_cast<const float4*>(pb);
            v.x += w.x; v.y += w.y; v.z += w.z; v.w += w.w;
        }
        float ri = 1.0f / (float)min(min(i + 1, 64 - i), 5);
        int jb = j4 << 2;
        float4 w;
        w.x = v.x * ri * (1.0f / (float)min(min(jb + 1, 64 - jb), 5));
        w.y = v.y * ri * (1.0f / (float)min(min(jb + 2, 63 - jb), 5));
        w.z = v.z * ri * (1.0f / (float)min(min(jb + 3, 62 - jb), 5));
        w.w = v.w * ri * (1.0f / (float)min(min(jb + 4, 61 - jb), 5));
        *reinterpret_cast<float4*>(&li[(ch * 5 + di) * LJS + jb]) = w;
    }
    __syncthreads();

    // emit: 60 pj x 100 float4, LUT-addressed, NON-TEMPORAL coalesced writes
    float* ob = out + ((size_t)im * NPATCH + (size_t)pi * OH) * CDIM + h0 * VF;
    for (int u = t; u < 6000; u += 256) {
        int pj = u / 100, r = u - 100 * pj;
        int4 e = lut[r];
        floatx4 o;
        o.x = li[e.x + pj];
        o.y = li[e.y + pj];
        o.z = li[e.z + pj];
        o.w = li[e.w + pj];
        __builtin_nontemporal_store(o,
            reinterpret_cast<floatx4*>(ob + (size_t)pj * CDIM + 4 * r));
    }
}

extern "C" void kernel_launch(void* const* d_in, const int* in_sizes, int n_in,
                              void* d_out, int out_size, void* d_ws, size_t ws_size,
                              hipStream_t stream) {
    const float* x = (const float*)d_in[0];
    float* slab = (float*)d_ws;                // 12*8*64*9*64 fl = 14.2 MB
    float* out  = (float*)d_out;

    // PROBE: fold launched twice (idempotent). dur_us - 76.2 = steady fold cost.
    fold_kernel<<<768, 512, 0, stream>>>(x, slab);
    fold_kernel<<<768, 512, 0, stream>>>(x, slab);
    unfold_kernel<<<1920, 256, 0, stream>>>(slab, out);

    (void)out_size; (void)ws_size; (void)in_sizes; (void)n_in;
}

// Round 17
// 77.464 us; speedup vs baseline: 1.4060x; 1.4060x over previous
//
#include <hip/hip_runtime.h>

// images=8, patches=3600(=60*60), hor_f=64, ver_f=25(=5*5), 64x64 px, k=5
#define OH     60
#define NIMG   8
#define HF     64
#define VF     25
#define NPATCH 3600
#define CDIM   1600                  // HF*VF

typedef float floatx4 __attribute__((ext_vector_type(4)));  // native vec for nt-store

// ---- fold (r15, unchanged): 1D grid 768, XCD-pinned: im = b & 7 ----
#define FH   8                       // h channels per block
#define FC   (FH * VF)               // 200 c values
#define SPI  5                       // pi rows per strip
#define PJS  64                      // pj stride (XOR-swizzled)
#define NSTRIP 12
#define SROWS  9                     // SPI + 4 halo rows

__global__ __launch_bounds__(512, 6) void fold_kernel(const float* __restrict__ x,
                                                      float* __restrict__ slab) {
    __shared__ float lb[FC * PJS];   // 51.2 KB
    const int b = blockIdx.x;
    const int im = b & 7;            // XCD pin (blockIdx round-robins mod 8)
    const int rem = b >> 3;          // 0..95
    const int hg = rem & 7, strip = rem >> 3;
    const int t = threadIdx.x;
    const int h0 = hg * FH;
    const int pi0 = strip * SPI;
    const int j = t & 63, g = t >> 6;          // g = local h (0..7)

    float acc[SROWS];
#pragma unroll
    for (int k = 0; k < SROWS; ++k) acc[k] = 0.f;

    const float* xb = x + ((size_t)im * NPATCH + (size_t)pi0 * OH) * CDIM + h0 * VF;

    int off_g[6], off_l[6];
#pragma unroll
    for (int k = 0; k < 6; ++k) {
        int u = t + 512 * k;
        if (u < 3000) {
            int pj = u / 50, c4 = u - 50 * pj;
            off_g[k] = pj * CDIM + (c4 << 2);
            off_l[k] = (c4 << 8) + (pj ^ (c4 & 31));
        }
    }

    float4 stg[6];
#pragma unroll
    for (int k = 0; k < 6; ++k)
        if (t + 512 * k < 3000)
            stg[k] = *reinterpret_cast<const float4*>(xb + off_g[k]);

#pragma unroll
    for (int row = 0; row < SPI; ++row) {
        if (row) __syncthreads();
#pragma unroll
        for (int k = 0; k < 6; ++k)
            if (t + 512 * k < 3000) {
                float4 v = stg[k];
                int a = off_l[k];
                lb[a]           = v.x;
                lb[a + PJS]     = v.y;
                lb[a + 2 * PJS] = v.z;
                lb[a + 3 * PJS] = v.w;
            }
        if (row + 1 < SPI) {                   // prefetch next row during compute
#pragma unroll
            for (int k = 0; k < 6; ++k)
                if (t + 512 * k < 3000)
                    stg[k] = *reinterpret_cast<const float4*>(
                        xb + (size_t)(row + 1) * OH * CDIM + off_g[k]);
        }
        __syncthreads();
#pragma unroll
        for (int di = 0; di < 5; ++di) {
#pragma unroll
            for (int dj = 0; dj < 5; ++dj) {
                int c = g * VF + di * 5 + dj;
                int pjr = j - dj;
                if ((unsigned)pjr < 60u)
                    acc[row + di] += lb[c * PJS + (pjr ^ ((c >> 2) & 31))];
            }
        }
    }

    float* sb = slab + (((size_t)(strip * 8 + im) * 64 + h0 + g) * SROWS) * 64 + j;
#pragma unroll
    for (int il = 0; il < SROWS; ++il) sb[il * 64] = acc[il];
}

// ---- unfold v5: 1D grid 1920 XCD-pinned; fixed thread roles, register LUT ----
#define UH   16                      // channels per block
#define LJS  68                      // padded j stride (f4-aligned)

__global__ __launch_bounds__(256) void unfold_kernel(const float* __restrict__ slab,
                                                     float* __restrict__ out) {
    __shared__ float li[UH * 5 * LJS];         // 5440 fl = 21.76 KB
    const int b = blockIdx.x;
    const int im = b & 7;            // XCD pin
    const int rem = b >> 3;          // 0..239
    const int hh = rem & 3, pi = rem >> 2;     // hh 0..3, pi 0..59
    const int t = threadIdx.x;
    const int h0 = hh * UH;

    // ---- stage: thread = (ch, j4); unrolled di loop; minimal VALU ----
    {
        const int ch = t >> 4, j4 = t & 15;
        const int jb = j4 << 2;
        float rc0 = 0.2f, rc1 = 0.2f, rc2 = 0.2f, rc3 = 0.2f;   // 1/cj per component
        if (j4 == 0)  { rc0 = 1.0f;  rc1 = 0.5f;       rc2 = 1.0f / 3.0f; rc3 = 0.25f; }
        if (j4 == 15) { rc0 = 0.25f; rc1 = 1.0f / 3.0f; rc2 = 0.5f;       rc3 = 1.0f; }
#pragma unroll
        for (int di = 0; di < 5; ++di) {
            int i = pi + di;
            int s_hi = min(i / 5, NSTRIP - 1);
            int s_lo = (i <= 8) ? 0 : (i - 4) / 5;
            const float* pa = slab +
                (((size_t)(s_lo * 8 + im) * 64 + h0 + ch) * SROWS + (i - 5 * s_lo)) * 64 + jb;
            float4 v = *reinterpret_cast<const float4*>(pa);
            if (s_hi != s_lo) {
                const float* pb = slab +
                    (((size_t)(s_hi * 8 + im) * 64 + h0 + ch) * SROWS + (i - 5 * s_hi)) * 64 + jb;
                float4 w2 = *reinterpret_cast<const float4*>(pb);
                v.x += w2.x; v.y += w2.y; v.z += w2.z; v.w += w2.w;
            }
            float ri = 0.2f;                   // 1/ci (border rows only differ)
            if (i < 4) ri = 1.0f / (float)(i + 1);
            else if (i > 59) ri = 1.0f / (float)(64 - i);
            float4 w;
            w.x = v.x * ri * rc0;
            w.y = v.y * ri * rc1;
            w.z = v.z * ri * rc2;
            w.w = v.w * ri * rc3;
            *reinterpret_cast<float4*>(&li[(ch * 5 + di) * LJS + jb]) = w;
        }
    }
    __syncthreads();

    // ---- emit: lane owns r (=lane, +64 if lane<36); wave owns pj stripe ----
    {
        const int lane = t & 63, wave = t >> 6;
        int e1x, e1y, e1z, e1w, e2x, e2y, e2z, e2w;
        {
            int fl0 = lane << 2;
#pragma unroll
            for (int k = 0; k < 4; ++k) {
                int fl = fl0 + k;              // r1 = lane
                int ho = fl / 25, v = fl - 25 * ho;
                int di = v / 5, dj = v - 5 * di;
                int e = (ho * 5 + di) * LJS + dj;
                if (k == 0) e1x = e; else if (k == 1) e1y = e;
                else if (k == 2) e1z = e; else e1w = e;
                int fl2 = fl + 256;            // r2 = lane + 64 (valid if lane < 36)
                int fl2c = min(fl2, 399);      // clamp decode (masked lanes harmless)
                int ho2 = fl2c / 25, v2 = fl2c - 25 * ho2;
                int di2 = v2 / 5, dj2 = v2 - 5 * di2;
                int e2 = (ho2 * 5 + di2) * LJS + dj2;
                if (k == 0) e2x = e2; else if (k == 1) e2y = e2;
                else if (k == 2) e2z = e2; else e2w = e2;
            }
        }
        float* p1 = out + ((size_t)im * NPATCH + (size_t)pi * OH + wave) * CDIM
                        + h0 * VF + (lane << 2);
        for (int pj = wave; pj < 60; pj += 4) {
            floatx4 o;
            o.x = li[e1x + pj];
            o.y = li[e1y + pj];
            o.z = li[e1z + pj];
            o.w = li[e1w + pj];
            __builtin_nontemporal_store(o, reinterpret_cast<floatx4*>(p1));
            if (lane < 36) {
                floatx4 o2;
                o2.x = li[e2x + pj];
                o2.y = li[e2y + pj];
                o2.z = li[e2z + pj];
                o2.w = li[e2w + pj];
                __builtin_nontemporal_store(o2, reinterpret_cast<floatx4*>(p1 + 256));
            }
            p1 += 4 * CDIM;
        }
    }
}

extern "C" void kernel_launch(void* const* d_in, const int* in_sizes, int n_in,
                              void* d_out, int out_size, void* d_ws, size_t ws_size,
                              hipStream_t stream) {
    const float* x = (const float*)d_in[0];
    float* slab = (float*)d_ws;                // 12*8*64*9*64 fl = 14.2 MB
    float* out  = (float*)d_out;

    fold_kernel<<<768, 512, 0, stream>>>(x, slab);      // 96 blocks per image/XCD
    unfold_kernel<<<1920, 256, 0, stream>>>(slab, out); // 240 blocks per image/XCD

    (void)out_size; (void)ws_size; (void)in_sizes; (void)n_in;
}